// Round 10
// baseline (252.208 us; speedup 1.0000x reference)
//
#include <hip/hip_runtime.h>
#include <hip/hip_fp16.h>

#define NNODES 100000
#define NBUCK 391                 // ceil(100000/256) buckets of 256 nodes (dst>>8)
#define NB_CHUNK 256              // edge chunks for counting sort
#define NC (NBUCK * NB_CHUNK)     // count-matrix size = 100096
#define SCAN_ELEMS 1024           // elements per scan block (256 threads x 4)

// ---------------- edge dtype sniffer (int64 vs int32) ----------------
__global__ void detect_kernel(const int* __restrict__ raw, int* __restrict__ flag) {
    __shared__ int cnt;
    if (threadIdx.x == 0) cnt = 0;
    __syncthreads();
    if (threadIdx.x < 100) {
        if (raw[2 * threadIdx.x + 1] == 0) atomicAdd(&cnt, 1);
    }
    __syncthreads();
    if (threadIdx.x == 0) *flag = (cnt > 50) ? 1 : 0;
}

// ---------------- counting sort pass 1: per-chunk bucket histogram ----------------
__global__ __launch_bounds__(256) void count_kernel(const int* __restrict__ raw,
                                                    int* __restrict__ counts,
                                                    int E, int CE, const int* __restrict__ flag) {
    __shared__ int hist[NBUCK];
    for (int i = threadIdx.x; i < NBUCK; i += 256) hist[i] = 0;
    __syncthreads();
    int b = blockIdx.x;
    int isI64 = *flag;
    int beg = b * CE;
    int end = beg + CE; if (end > E) end = E;
    for (int e = beg + (int)threadIdx.x; e < end; e += 256) {
        int d = isI64 ? raw[2 * E + 2 * e] : raw[E + e];
        atomicAdd(&hist[d >> 8], 1);              // LDS atomic
    }
    __syncthreads();
    for (int k = threadIdx.x; k < NBUCK; k += 256)
        counts[k * NB_CHUNK + b] = hist[k];       // bucket-major for linear scan
}

// ---------------- device-wide exclusive scan (generic) ----------------
__global__ __launch_bounds__(256) void scan_partial_kernel(const int* __restrict__ in,
                                                           int* __restrict__ bsum, int n) {
    int base = blockIdx.x * SCAN_ELEMS + threadIdx.x * 4;
    int s = 0;
    if (base + 3 < n) {
        int4 v = *reinterpret_cast<const int4*>(&in[base]);
        s = v.x + v.y + v.z + v.w;
    } else {
        for (int i = base; i < n && i < base + 4; ++i) s += in[i];
    }
#pragma unroll
    for (int d = 32; d; d >>= 1) s += __shfl_down(s, d, 64);
    __shared__ int ws[4];
    int wid = threadIdx.x >> 6;
    if ((threadIdx.x & 63) == 0) ws[wid] = s;
    __syncthreads();
    if (threadIdx.x == 0) bsum[blockIdx.x] = ws[0] + ws[1] + ws[2] + ws[3];
}

__global__ void scan_partials_kernel(const int* __restrict__ bsum, int* __restrict__ boff,
                                     int* __restrict__ total_out, int nb) {
    __shared__ int s[128];
    int t = threadIdx.x;
    s[t] = (t < nb) ? bsum[t] : 0;
    __syncthreads();
    for (int d = 1; d < 128; d <<= 1) {
        int v = (t >= d) ? s[t - d] : 0;
        __syncthreads();
        s[t] += v;
        __syncthreads();
    }
    if (t < nb) boff[t] = (t == 0) ? 0 : s[t - 1];
    if (t == 127) *total_out = s[127];
}

__global__ __launch_bounds__(256) void scan_write_kernel(const int* __restrict__ in,
                                                         const int* __restrict__ boff,
                                                         int* __restrict__ outp, int n) {
    __shared__ int ts[256];
    int base = blockIdx.x * SCAN_ELEMS + threadIdx.x * 4;
    int v0 = 0, v1 = 0, v2 = 0, v3 = 0;
    if (base + 3 < n) {
        int4 v = *reinterpret_cast<const int4*>(&in[base]);
        v0 = v.x; v1 = v.y; v2 = v.z; v3 = v.w;
    } else {
        if (base < n)     v0 = in[base];
        if (base + 1 < n) v1 = in[base + 1];
        if (base + 2 < n) v2 = in[base + 2];
    }
    ts[threadIdx.x] = v0 + v1 + v2 + v3;
    __syncthreads();
    for (int d = 1; d < 256; d <<= 1) {
        int t = (threadIdx.x >= d) ? ts[threadIdx.x - d] : 0;
        __syncthreads();
        ts[threadIdx.x] += t;
        __syncthreads();
    }
    int run = boff[blockIdx.x] + ((threadIdx.x == 0) ? 0 : ts[threadIdx.x - 1]);
    if (base < n)     { outp[base] = run;     run += v0; }
    if (base + 1 < n) { outp[base + 1] = run; run += v1; }
    if (base + 2 < n) { outp[base + 2] = run; run += v2; }
    if (base + 3 < n) { outp[base + 3] = run; }
}

// ---------------- counting sort pass 2: scatter (packed: src | (d&255)<<24) ----------------
__global__ __launch_bounds__(256) void scatter_kernel(const int* __restrict__ raw,
                                                      const int* __restrict__ cbase,
                                                      int* __restrict__ cw,
                                                      int E, int CE, const int* __restrict__ flag) {
    __shared__ int cur[NBUCK];
    int b = blockIdx.x;
    for (int k = threadIdx.x; k < NBUCK; k += 256)
        cur[k] = cbase[k * NB_CHUNK + b];
    __syncthreads();
    int isI64 = *flag;
    int beg = b * CE;
    int end = beg + CE; if (end > E) end = E;
    for (int e = beg + (int)threadIdx.x; e < end; e += 256) {
        int s, d;
        if (isI64) { s = raw[2 * e]; d = raw[2 * E + 2 * e]; }
        else       { s = raw[e];     d = raw[E + e]; }
        int pos = atomicAdd(&cur[d >> 8], 1);     // LDS atomic
        cw[pos] = s | ((d & 255) << 24);          // single-CU contiguous run per bucket
    }
}

// ---------------- per-bucket degree histogram + dinv (coalesced, atomic-free) ----------------
__global__ __launch_bounds__(256) void histdeg_kernel(const int* __restrict__ cw,
                                                      const int* __restrict__ cbase,
                                                      int* __restrict__ indeg,
                                                      float* __restrict__ dinv, int n) {
    __shared__ int hist[256];
    hist[threadIdx.x] = 0;
    __syncthreads();
    int k = blockIdx.x;
    int beg = cbase[k * NB_CHUNK];
    int end = cbase[(k + 1) * NB_CHUNK];
    for (int e = beg + (int)threadIdx.x; e < end; e += 256)
        atomicAdd(&hist[(cw[e] >> 24) & 255], 1); // LDS atomic
    __syncthreads();
    int i = (k << 8) + threadIdx.x;
    if (i < n) {
        int dg = hist[threadIdx.x];
        indeg[i] = dg;
        dinv[i] = rsqrtf((float)(dg + 1));        // +1 self loop; always > 0
    }
}

// ---------------- per-bucket CSR col fill (LDS cursors, single-CU-owned window) ----------------
__global__ __launch_bounds__(256) void fillcol_kernel(const int* __restrict__ cw,
                                                      const int* __restrict__ cbase,
                                                      const int* __restrict__ ptr,
                                                      int* __restrict__ col, int n) {
    __shared__ int cur[256];
    int k = blockIdx.x;
    int i = (k << 8) + threadIdx.x;
    cur[threadIdx.x] = (i < n) ? ptr[i] : 0;
    __syncthreads();
    int beg = cbase[k * NB_CHUNK];
    int end = cbase[(k + 1) * NB_CHUNK];
    for (int e = beg + (int)threadIdx.x; e < end; e += 256) {
        int v = cw[e];
        int pos = atomicAdd(&cur[(v >> 24) & 255], 1); // LDS atomic; pos is global index
        col[pos] = v & 0x00FFFFFF;
    }
}

// ---------------- GEMM1: [M,256] @ [256,64] -> fp16 [M,64] ----------------
// 8x8 register tile (64 FMA per kk vs 4 ds_read_b128 -> VALU ceiling 67% of the
// shared per-CU LDS unit, vs 44% at 4x8). 256 threads, BM=256 (391 blocks).
// Register-prefetch of the next K-tile hides global latency under the kk loop.
__global__ __launch_bounds__(256) void gemm1_kernel(const float* __restrict__ x,
                                                    const float* __restrict__ W,
                                                    __half* __restrict__ H, int M) {
    __shared__ float xs_t[32][258];    // [k][row], padded: transp. stores <=2-way
    __shared__ float ws[32][66];
    int tid = threadIdx.x;
    int tx = tid & 7;                  // 8 col-groups of 8
    int ty = tid >> 3;                 // 32 row-groups of 8
    int bm = blockIdx.x * 256;
    const float4* x4 = reinterpret_cast<const float4*>(x);
    float4 xr[8], wr[2];

#define G1_LOAD(KT)                                                              \
    {                                                                            \
        _Pragma("unroll")                                                        \
        for (int i = 0; i < 8; ++i) {                                            \
            int lin = i * 256 + tid;                                             \
            int row = lin >> 3;                                                  \
            int kg  = lin & 7;                                                   \
            int gr = bm + row; if (gr >= M) gr = M - 1;                          \
            xr[i] = x4[(size_t)gr * 64 + (KT) * 8 + kg];                         \
        }                                                                        \
        _Pragma("unroll")                                                        \
        for (int i = 0; i < 2; ++i) {                                            \
            int lin = i * 256 + tid;                                             \
            int r = lin >> 4;                                                    \
            int c = (lin & 15) << 2;                                             \
            wr[i] = *reinterpret_cast<const float4*>(&W[(size_t)((KT) * 32 + r) * 64 + c]); \
        }                                                                        \
    }

    float acc[8][8] = {};
    G1_LOAD(0);
    for (int kt = 0; kt < 8; ++kt) {
        // write staged tile to LDS
#pragma unroll
        for (int i = 0; i < 8; ++i) {
            int lin = i * 256 + tid;
            int row = lin >> 3;
            int kg  = lin & 7;
            xs_t[kg * 4 + 0][row] = xr[i].x;
            xs_t[kg * 4 + 1][row] = xr[i].y;
            xs_t[kg * 4 + 2][row] = xr[i].z;
            xs_t[kg * 4 + 3][row] = xr[i].w;
        }
#pragma unroll
        for (int i = 0; i < 2; ++i) {
            int lin = i * 256 + tid;
            int r = lin >> 4;
            int c = (lin & 15) << 2;
            *reinterpret_cast<float4*>(&ws[r][c]) = wr[i];
        }
        __syncthreads();
        if (kt < 7) G1_LOAD(kt + 1);   // prefetch next tile under compute
#pragma unroll 8
        for (int kk = 0; kk < 32; ++kk) {
            float4 a0 = *reinterpret_cast<const float4*>(&xs_t[kk][ty * 8]);
            float4 a1 = *reinterpret_cast<const float4*>(&xs_t[kk][ty * 8 + 4]);
            float4 b0 = *reinterpret_cast<const float4*>(&ws[kk][tx * 8]);
            float4 b1 = *reinterpret_cast<const float4*>(&ws[kk][tx * 8 + 4]);
            float av[8] = {a0.x, a0.y, a0.z, a0.w, a1.x, a1.y, a1.z, a1.w};
            float bv[8] = {b0.x, b0.y, b0.z, b0.w, b1.x, b1.y, b1.z, b1.w};
#pragma unroll
            for (int i = 0; i < 8; ++i)
#pragma unroll
                for (int j = 0; j < 8; ++j)
                    acc[i][j] = fmaf(av[i], bv[j], acc[i][j]);
        }
        __syncthreads();
    }
#undef G1_LOAD
#pragma unroll
    for (int i = 0; i < 8; ++i) {
        int gr = bm + ty * 8 + i;
        if (gr >= M) continue;
        __half hv[8];
#pragma unroll
        for (int j = 0; j < 8; ++j) hv[j] = __float2half(acc[i][j]);
        *reinterpret_cast<uint4*>(&H[(size_t)gr * 64 + tx * 8]) =
            *reinterpret_cast<const uint4*>(hv);
    }
}

// ---------------- aggregation: fp16 gathers, 8-lane groups (8 edges/instr) ----------------
__global__ __launch_bounds__(256) void aggregate_kernel(const __half* __restrict__ h,
                                                        const int* __restrict__ ptr,
                                                        const int* __restrict__ col,
                                                        const float* __restrict__ dinv,
                                                        const float* __restrict__ bias,
                                                        void* __restrict__ out, int n,
                                                        int relu, int out_half) {
    int node = (blockIdx.x << 2) + (threadIdx.x >> 6);
    if (node >= n) return;
    int lane = threadIdx.x & 63;
    int g  = lane >> 3;               // edge-group 0..7
    int fl = (lane & 7) << 3;         // feature base: 0,8,...,56
    float acc[8] = {};
    int pend = ptr[node + 1];
    int p = ptr[node] + g;
    for (; p + 8 < pend; p += 16) {   // unroll 2: 16 edges in flight per wave
        int c0 = col[p];
        int c1 = col[p + 8];
        uint4 r0 = *reinterpret_cast<const uint4*>(&h[(size_t)c0 * 64 + fl]);
        uint4 r1 = *reinterpret_cast<const uint4*>(&h[(size_t)c1 * 64 + fl]);
        float w0 = dinv[c0], w1 = dinv[c1];
        const unsigned* u0 = &r0.x;
        const unsigned* u1 = &r1.x;
#pragma unroll
        for (int k = 0; k < 4; ++k) {
            float2 f0 = __half22float2(*reinterpret_cast<const __half2*>(&u0[k]));
            float2 f1 = __half22float2(*reinterpret_cast<const __half2*>(&u1[k]));
            acc[2 * k]     = fmaf(w0, f0.x, acc[2 * k]);
            acc[2 * k + 1] = fmaf(w0, f0.y, acc[2 * k + 1]);
            acc[2 * k]     = fmaf(w1, f1.x, acc[2 * k]);
            acc[2 * k + 1] = fmaf(w1, f1.y, acc[2 * k + 1]);
        }
    }
    if (p < pend) {
        int c0 = col[p];
        uint4 r0 = *reinterpret_cast<const uint4*>(&h[(size_t)c0 * 64 + fl]);
        float w0 = dinv[c0];
        const unsigned* u0 = &r0.x;
#pragma unroll
        for (int k = 0; k < 4; ++k) {
            float2 f0 = __half22float2(*reinterpret_cast<const __half2*>(&u0[k]));
            acc[2 * k]     = fmaf(w0, f0.x, acc[2 * k]);
            acc[2 * k + 1] = fmaf(w0, f0.y, acc[2 * k + 1]);
        }
    }
#pragma unroll
    for (int j = 0; j < 8; ++j) {
        acc[j] += __shfl_xor(acc[j], 8, 64);
        acc[j] += __shfl_xor(acc[j], 16, 64);
        acc[j] += __shfl_xor(acc[j], 32, 64);
    }
    if (g == 0) {                     // lanes 0..7 own the epilogue
        float di = dinv[node];
        uint4 sv = *reinterpret_cast<const uint4*>(&h[(size_t)node * 64 + fl]);
        const unsigned* su = &sv.x;
        float v[8];
#pragma unroll
        for (int k = 0; k < 4; ++k) {
            float2 f = __half22float2(*reinterpret_cast<const __half2*>(&su[k]));
            v[2 * k]     = fmaf(di, f.x, acc[2 * k]) * di;
            v[2 * k + 1] = fmaf(di, f.y, acc[2 * k + 1]) * di;
        }
        if (bias) {
            float4 b0 = *reinterpret_cast<const float4*>(&bias[fl]);
            float4 b1 = *reinterpret_cast<const float4*>(&bias[fl + 4]);
            v[0] += b0.x; v[1] += b0.y; v[2] += b0.z; v[3] += b0.w;
            v[4] += b1.x; v[5] += b1.y; v[6] += b1.z; v[7] += b1.w;
        }
        if (relu) {
#pragma unroll
            for (int j = 0; j < 8; ++j) v[j] = fmaxf(v[j], 0.f);
        }
        if (out_half) {
            __half hv[8];
#pragma unroll
            for (int j = 0; j < 8; ++j) hv[j] = __float2half(v[j]);
            *reinterpret_cast<uint4*>(&((__half*)out)[(size_t)node * 64 + fl]) =
                *reinterpret_cast<const uint4*>(hv);
        } else {
            float* fo = (float*)out;
            *reinterpret_cast<float4*>(&fo[(size_t)node * 64 + fl]) =
                make_float4(v[0], v[1], v[2], v[3]);
            *reinterpret_cast<float4*>(&fo[(size_t)node * 64 + fl + 4]) =
                make_float4(v[4], v[5], v[6], v[7]);
        }
    }
}

// ---------------- GEMM2: [M,64] @ [64,128] + b -> [M,128] ----------------
__global__ __launch_bounds__(256) void gemm2_kernel(const float* __restrict__ A,
                                                    const float* __restrict__ W,
                                                    const float* __restrict__ bias,
                                                    float* __restrict__ out, int M) {
    __shared__ float as[64][65];
    __shared__ float ws[64][128];
    int tid = threadIdx.x;
    int bm = blockIdx.x * 64;
    int ty = tid >> 4, tx = tid & 15;
#pragma unroll
    for (int i = 0; i < 4; ++i) {
        int lin = (tid << 2) + i;
        int r = lin >> 4;
        int c = (lin & 15) << 2;
        float4 v = make_float4(0.f, 0.f, 0.f, 0.f);
        int gr = bm + r;
        if (gr < M) v = *reinterpret_cast<const float4*>(&A[(size_t)gr * 64 + c]);
        as[r][c] = v.x; as[r][c + 1] = v.y; as[r][c + 2] = v.z; as[r][c + 3] = v.w;
    }
#pragma unroll
    for (int i = 0; i < 8; ++i) {
        int lin = tid + (i << 8);
        int r = lin >> 5;
        int c = (lin & 31) << 2;
        *reinterpret_cast<float4*>(&ws[r][c]) =
            *reinterpret_cast<const float4*>(&W[(size_t)r * 128 + c]);
    }
    __syncthreads();
    float acc[4][8] = {};
#pragma unroll 8
    for (int kk = 0; kk < 64; ++kk) {
        float a[4];
#pragma unroll
        for (int i = 0; i < 4; ++i) a[i] = as[ty * 4 + i][kk];
        float b[8];
        float4 b0 = *reinterpret_cast<const float4*>(&ws[kk][tx * 8]);
        float4 b1 = *reinterpret_cast<const float4*>(&ws[kk][tx * 8 + 4]);
        b[0] = b0.x; b[1] = b0.y; b[2] = b0.z; b[3] = b0.w;
        b[4] = b1.x; b[5] = b1.y; b[6] = b1.z; b[7] = b1.w;
#pragma unroll
        for (int i = 0; i < 4; ++i)
#pragma unroll
            for (int j = 0; j < 8; ++j)
                acc[i][j] = fmaf(a[i], b[j], acc[i][j]);
    }
#pragma unroll
    for (int i = 0; i < 4; ++i) {
        int gr = bm + ty * 4 + i;
        if (gr >= M) continue;
#pragma unroll
        for (int jv = 0; jv < 2; ++jv) {
            int cbase = tx * 8 + jv * 4;
            float4 o;
            o.x = acc[i][jv * 4 + 0] + bias[cbase + 0];
            o.y = acc[i][jv * 4 + 1] + bias[cbase + 1];
            o.z = acc[i][jv * 4 + 2] + bias[cbase + 2];
            o.w = acc[i][jv * 4 + 3] + bias[cbase + 3];
            *reinterpret_cast<float4*>(&out[(size_t)gr * 128 + cbase]) = o;
        }
    }
}

extern "C" void kernel_launch(void* const* d_in, const int* in_sizes, int n_in,
                              void* d_out, int out_size, void* d_ws, size_t ws_size,
                              hipStream_t stream) {
    const float* x  = (const float*)d_in[0];
    const int*   ei = (const int*)d_in[1];
    const float* W1 = (const float*)d_in[2];
    const float* b1 = (const float*)d_in[3];
    const float* W2 = (const float*)d_in[4];
    const float* b2 = (const float*)d_in[5];
    float* out = (float*)d_out;
    const int n = NNODES;
    const int E = in_sizes[1] / 2;
    const int CE = (E + NB_CHUNK - 1) / NB_CHUNK;

    char* w = (char*)d_ws;
    auto alloc = [&](size_t bytes) {
        char* p = w;
        w += (bytes + 255) & ~(size_t)255;
        return p;
    };
    int*    flag   = (int*)   alloc(4);
    int*    counts = (int*)   alloc((size_t)NC * 4);
    int*    cbase  = (int*)   alloc((size_t)(NC + 1) * 4);
    int*    indeg  = (int*)   alloc((size_t)n * 4);
    float*  dinv   = (float*) alloc((size_t)n * 4);
    int*    ptr    = (int*)   alloc((size_t)(n + 1) * 4);
    int*    bsum   = (int*)   alloc(128 * 4);
    int*    boff   = (int*)   alloc(128 * 4);
    int*    cw     = (int*)   alloc((size_t)E * 4);
    int*    col    = (int*)   alloc((size_t)E * 4);
    __half* H1     = (__half*)alloc((size_t)n * 64 * 2);
    __half* h1     = (__half*)alloc((size_t)n * 64 * 2);
    float*  A2     = (float*) alloc((size_t)n * 64 * 4);

    int sbC = (NC + SCAN_ELEMS - 1) / SCAN_ELEMS;   // 98
    int sbN = (n  + SCAN_ELEMS - 1) / SCAN_ELEMS;   // 98

    detect_kernel<<<1, 128, 0, stream>>>(ei, flag);
    count_kernel<<<NB_CHUNK, 256, 0, stream>>>(ei, counts, E, CE, flag);
    scan_partial_kernel<<<sbC, 256, 0, stream>>>(counts, bsum, NC);
    scan_partials_kernel<<<1, 128, 0, stream>>>(bsum, boff, &cbase[NC], sbC);
    scan_write_kernel<<<sbC, 256, 0, stream>>>(counts, boff, cbase, NC);
    scatter_kernel<<<NB_CHUNK, 256, 0, stream>>>(ei, cbase, cw, E, CE, flag);
    histdeg_kernel<<<NBUCK, 256, 0, stream>>>(cw, cbase, indeg, dinv, n);
    scan_partial_kernel<<<sbN, 256, 0, stream>>>(indeg, bsum, n);
    scan_partials_kernel<<<1, 128, 0, stream>>>(bsum, boff, &ptr[n], sbN);
    scan_write_kernel<<<sbN, 256, 0, stream>>>(indeg, boff, ptr, n);
    fillcol_kernel<<<NBUCK, 256, 0, stream>>>(cw, cbase, ptr, col, n);

    gemm1_kernel<<<(n + 255) / 256, 256, 0, stream>>>(x, W1, H1, n);
    aggregate_kernel<<<(n + 3) / 4, 256, 0, stream>>>(H1, ptr, col, dinv, b1, h1, n, 1, 1);
    aggregate_kernel<<<(n + 3) / 4, 256, 0, stream>>>(h1, ptr, col, dinv, nullptr, A2, n, 0, 0);
    gemm2_kernel<<<(n + 63) / 64, 256, 0, stream>>>(A2, W2, b2, out, n);
}

// Round 11
// 250.914 us; speedup vs baseline: 1.0052x; 1.0052x over previous
//
#include <hip/hip_runtime.h>
#include <hip/hip_fp16.h>

#define NNODES 100000
#define NBUCK 391                 // ceil(100000/256) buckets of 256 nodes (dst>>8)
#define NB_CHUNK 256              // edge chunks for counting sort
#define NC (NBUCK * NB_CHUNK)     // count-matrix size = 100096
#define SCAN_ELEMS 1024           // elements per scan block (256 threads x 4)

// ---------------- edge dtype sniffer (int64 vs int32) ----------------
__global__ void detect_kernel(const int* __restrict__ raw, int* __restrict__ flag) {
    __shared__ int cnt;
    if (threadIdx.x == 0) cnt = 0;
    __syncthreads();
    if (threadIdx.x < 100) {
        if (raw[2 * threadIdx.x + 1] == 0) atomicAdd(&cnt, 1);
    }
    __syncthreads();
    if (threadIdx.x == 0) *flag = (cnt > 50) ? 1 : 0;
}

// ---------------- counting sort pass 1: per-chunk bucket histogram ----------------
__global__ __launch_bounds__(256) void count_kernel(const int* __restrict__ raw,
                                                    int* __restrict__ counts,
                                                    int E, int CE, const int* __restrict__ flag) {
    __shared__ int hist[NBUCK];
    for (int i = threadIdx.x; i < NBUCK; i += 256) hist[i] = 0;
    __syncthreads();
    int b = blockIdx.x;
    int isI64 = *flag;
    int beg = b * CE;
    int end = beg + CE; if (end > E) end = E;
    for (int e = beg + (int)threadIdx.x; e < end; e += 256) {
        int d = isI64 ? raw[2 * E + 2 * e] : raw[E + e];
        atomicAdd(&hist[d >> 8], 1);              // LDS atomic
    }
    __syncthreads();
    for (int k = threadIdx.x; k < NBUCK; k += 256)
        counts[k * NB_CHUNK + b] = hist[k];       // bucket-major for linear scan
}

// ---------------- device-wide exclusive scan (generic) ----------------
__global__ __launch_bounds__(256) void scan_partial_kernel(const int* __restrict__ in,
                                                           int* __restrict__ bsum, int n) {
    int base = blockIdx.x * SCAN_ELEMS + threadIdx.x * 4;
    int s = 0;
    if (base + 3 < n) {
        int4 v = *reinterpret_cast<const int4*>(&in[base]);
        s = v.x + v.y + v.z + v.w;
    } else {
        for (int i = base; i < n && i < base + 4; ++i) s += in[i];
    }
#pragma unroll
    for (int d = 32; d; d >>= 1) s += __shfl_down(s, d, 64);
    __shared__ int ws[4];
    int wid = threadIdx.x >> 6;
    if ((threadIdx.x & 63) == 0) ws[wid] = s;
    __syncthreads();
    if (threadIdx.x == 0) bsum[blockIdx.x] = ws[0] + ws[1] + ws[2] + ws[3];
}

__global__ void scan_partials_kernel(const int* __restrict__ bsum, int* __restrict__ boff,
                                     int* __restrict__ total_out, int nb) {
    __shared__ int s[128];
    int t = threadIdx.x;
    s[t] = (t < nb) ? bsum[t] : 0;
    __syncthreads();
    for (int d = 1; d < 128; d <<= 1) {
        int v = (t >= d) ? s[t - d] : 0;
        __syncthreads();
        s[t] += v;
        __syncthreads();
    }
    if (t < nb) boff[t] = (t == 0) ? 0 : s[t - 1];
    if (t == 127) *total_out = s[127];
}

__global__ __launch_bounds__(256) void scan_write_kernel(const int* __restrict__ in,
                                                         const int* __restrict__ boff,
                                                         int* __restrict__ outp, int n) {
    __shared__ int ts[256];
    int base = blockIdx.x * SCAN_ELEMS + threadIdx.x * 4;
    int v0 = 0, v1 = 0, v2 = 0, v3 = 0;
    if (base + 3 < n) {
        int4 v = *reinterpret_cast<const int4*>(&in[base]);
        v0 = v.x; v1 = v.y; v2 = v.z; v3 = v.w;
    } else {
        if (base < n)     v0 = in[base];
        if (base + 1 < n) v1 = in[base + 1];
        if (base + 2 < n) v2 = in[base + 2];
    }
    ts[threadIdx.x] = v0 + v1 + v2 + v3;
    __syncthreads();
    for (int d = 1; d < 256; d <<= 1) {
        int t = (threadIdx.x >= d) ? ts[threadIdx.x - d] : 0;
        __syncthreads();
        ts[threadIdx.x] += t;
        __syncthreads();
    }
    int run = boff[blockIdx.x] + ((threadIdx.x == 0) ? 0 : ts[threadIdx.x - 1]);
    if (base < n)     { outp[base] = run;     run += v0; }
    if (base + 1 < n) { outp[base + 1] = run; run += v1; }
    if (base + 2 < n) { outp[base + 2] = run; run += v2; }
    if (base + 3 < n) { outp[base + 3] = run; }
}

// ---------------- counting sort pass 2: scatter (packed: src | (d&255)<<24) ----------------
__global__ __launch_bounds__(256) void scatter_kernel(const int* __restrict__ raw,
                                                      const int* __restrict__ cbase,
                                                      int* __restrict__ cw,
                                                      int E, int CE, const int* __restrict__ flag) {
    __shared__ int cur[NBUCK];
    int b = blockIdx.x;
    for (int k = threadIdx.x; k < NBUCK; k += 256)
        cur[k] = cbase[k * NB_CHUNK + b];
    __syncthreads();
    int isI64 = *flag;
    int beg = b * CE;
    int end = beg + CE; if (end > E) end = E;
    for (int e = beg + (int)threadIdx.x; e < end; e += 256) {
        int s, d;
        if (isI64) { s = raw[2 * e]; d = raw[2 * E + 2 * e]; }
        else       { s = raw[e];     d = raw[E + e]; }
        int pos = atomicAdd(&cur[d >> 8], 1);     // LDS atomic
        cw[pos] = s | ((d & 255) << 24);          // single-CU contiguous run per bucket
    }
}

// ---------------- per-bucket degree histogram + dinv (coalesced, atomic-free) ----------------
__global__ __launch_bounds__(256) void histdeg_kernel(const int* __restrict__ cw,
                                                      const int* __restrict__ cbase,
                                                      int* __restrict__ indeg,
                                                      float* __restrict__ dinv, int n) {
    __shared__ int hist[256];
    hist[threadIdx.x] = 0;
    __syncthreads();
    int k = blockIdx.x;
    int beg = cbase[k * NB_CHUNK];
    int end = cbase[(k + 1) * NB_CHUNK];
    for (int e = beg + (int)threadIdx.x; e < end; e += 256)
        atomicAdd(&hist[(cw[e] >> 24) & 255], 1); // LDS atomic
    __syncthreads();
    int i = (k << 8) + threadIdx.x;
    if (i < n) {
        int dg = hist[threadIdx.x];
        indeg[i] = dg;
        dinv[i] = rsqrtf((float)(dg + 1));        // +1 self loop; always > 0
    }
}

// ---------------- per-bucket CSR col fill (LDS cursors, single-CU-owned window) ----------------
__global__ __launch_bounds__(256) void fillcol_kernel(const int* __restrict__ cw,
                                                      const int* __restrict__ cbase,
                                                      const int* __restrict__ ptr,
                                                      int* __restrict__ col, int n) {
    __shared__ int cur[256];
    int k = blockIdx.x;
    int i = (k << 8) + threadIdx.x;
    cur[threadIdx.x] = (i < n) ? ptr[i] : 0;
    __syncthreads();
    int beg = cbase[k * NB_CHUNK];
    int end = cbase[(k + 1) * NB_CHUNK];
    for (int e = beg + (int)threadIdx.x; e < end; e += 256) {
        int v = cw[e];
        int pos = atomicAdd(&cur[(v >> 24) & 255], 1); // LDS atomic; pos is global index
        col[pos] = v & 0x00FFFFFF;
    }
}

// ---------------- GEMM1: [M,256] @ [256,64] -> fp16 [M,64] ----------------
// 8x8 register tile with SPLIT fragments: per-thread rows {ty*4+i, 64+ty*4+i},
// cols {tx*4+j, 32+tx*4+j}. Every ds_read_b128's 8 distinct lane addresses span
// exactly 128B (one bank sweep) -> conflict-free (r10's 256B span was 2-way).
// 128 threads, BM=128 -> 782 blocks (3.05/CU). Next-tile register prefetch.
__global__ __launch_bounds__(128) void gemm1_kernel(const float* __restrict__ x,
                                                    const float* __restrict__ W,
                                                    __half* __restrict__ H, int M) {
    __shared__ float xs_t[32][130];    // [k][row]; 130%32=2 -> reads (2kk+4ty)%32 distinct
    __shared__ float ws[32][66];
    int tid = threadIdx.x;
    int tx = tid & 7;                  // 8 col-groups
    int ty = tid >> 3;                 // 16 row-groups
    int bm = blockIdx.x * 128;
    const float4* x4 = reinterpret_cast<const float4*>(x);
    float4 xr[8], wr[4];

#define G1_LOAD(KT)                                                              \
    {                                                                            \
        _Pragma("unroll")                                                        \
        for (int i = 0; i < 8; ++i) {                                            \
            int lin = i * 128 + tid;                                             \
            int row = lin >> 3;                                                  \
            int kg  = lin & 7;                                                   \
            int gr = bm + row; if (gr >= M) gr = M - 1;                          \
            xr[i] = x4[(size_t)gr * 64 + (KT) * 8 + kg];                         \
        }                                                                        \
        _Pragma("unroll")                                                        \
        for (int i = 0; i < 4; ++i) {                                            \
            int lin = i * 128 + tid;                                             \
            int r = lin >> 4;                                                    \
            int c = (lin & 15) << 2;                                             \
            wr[i] = *reinterpret_cast<const float4*>(&W[(size_t)((KT) * 32 + r) * 64 + c]); \
        }                                                                        \
    }

    float acc[8][8] = {};
    G1_LOAD(0);
    for (int kt = 0; kt < 8; ++kt) {
        // write staged tile to LDS (transposed x; <=2-way on stores: free)
#pragma unroll
        for (int i = 0; i < 8; ++i) {
            int lin = i * 128 + tid;
            int row = lin >> 3;
            int kg  = lin & 7;
            xs_t[kg * 4 + 0][row] = xr[i].x;
            xs_t[kg * 4 + 1][row] = xr[i].y;
            xs_t[kg * 4 + 2][row] = xr[i].z;
            xs_t[kg * 4 + 3][row] = xr[i].w;
        }
#pragma unroll
        for (int i = 0; i < 4; ++i) {
            int lin = i * 128 + tid;
            int r = lin >> 4;
            int c = (lin & 15) << 2;
            *reinterpret_cast<float4*>(&ws[r][c]) = wr[i];
        }
        __syncthreads();
        if (kt < 7) G1_LOAD(kt + 1);   // prefetch next tile under compute
#pragma unroll 4
        for (int kk = 0; kk < 32; ++kk) {
            float4 a0 = *reinterpret_cast<const float4*>(&xs_t[kk][ty * 4]);
            float4 a1 = *reinterpret_cast<const float4*>(&xs_t[kk][64 + ty * 4]);
            float4 b0 = *reinterpret_cast<const float4*>(&ws[kk][tx * 4]);
            float4 b1 = *reinterpret_cast<const float4*>(&ws[kk][32 + tx * 4]);
            float av[8] = {a0.x, a0.y, a0.z, a0.w, a1.x, a1.y, a1.z, a1.w};
            float bv[8] = {b0.x, b0.y, b0.z, b0.w, b1.x, b1.y, b1.z, b1.w};
#pragma unroll
            for (int i = 0; i < 8; ++i)
#pragma unroll
                for (int j = 0; j < 8; ++j)
                    acc[i][j] = fmaf(av[i], bv[j], acc[i][j]);
        }
        __syncthreads();
    }
#undef G1_LOAD
    // epilogue: rows {bm+ty*4+i, bm+64+ty*4+i}, cols {tx*4+j, 32+tx*4+j}
#pragma unroll
    for (int half = 0; half < 2; ++half) {
#pragma unroll
        for (int i = 0; i < 4; ++i) {
            int gr = bm + half * 64 + ty * 4 + i;
            if (gr >= M) continue;
            int ai = half * 4 + i;
            __half hv0[4], hv1[4];
#pragma unroll
            for (int j = 0; j < 4; ++j) {
                hv0[j] = __float2half(acc[ai][j]);
                hv1[j] = __float2half(acc[ai][4 + j]);
            }
            *reinterpret_cast<uint2*>(&H[(size_t)gr * 64 + tx * 4]) =
                *reinterpret_cast<const uint2*>(hv0);
            *reinterpret_cast<uint2*>(&H[(size_t)gr * 64 + 32 + tx * 4]) =
                *reinterpret_cast<const uint2*>(hv1);
        }
    }
}

// ---------------- aggregation: fp16 gathers, 8-lane groups (8 edges/instr) ----------------
__global__ __launch_bounds__(256) void aggregate_kernel(const __half* __restrict__ h,
                                                        const int* __restrict__ ptr,
                                                        const int* __restrict__ col,
                                                        const float* __restrict__ dinv,
                                                        const float* __restrict__ bias,
                                                        void* __restrict__ out, int n,
                                                        int relu, int out_half) {
    int node = (blockIdx.x << 2) + (threadIdx.x >> 6);
    if (node >= n) return;
    int lane = threadIdx.x & 63;
    int g  = lane >> 3;               // edge-group 0..7
    int fl = (lane & 7) << 3;         // feature base: 0,8,...,56
    float acc[8] = {};
    int pend = ptr[node + 1];
    int p = ptr[node] + g;
    for (; p + 8 < pend; p += 16) {   // unroll 2: 16 edges in flight per wave
        int c0 = col[p];
        int c1 = col[p + 8];
        uint4 r0 = *reinterpret_cast<const uint4*>(&h[(size_t)c0 * 64 + fl]);
        uint4 r1 = *reinterpret_cast<const uint4*>(&h[(size_t)c1 * 64 + fl]);
        float w0 = dinv[c0], w1 = dinv[c1];
        const unsigned* u0 = &r0.x;
        const unsigned* u1 = &r1.x;
#pragma unroll
        for (int k = 0; k < 4; ++k) {
            float2 f0 = __half22float2(*reinterpret_cast<const __half2*>(&u0[k]));
            float2 f1 = __half22float2(*reinterpret_cast<const __half2*>(&u1[k]));
            acc[2 * k]     = fmaf(w0, f0.x, acc[2 * k]);
            acc[2 * k + 1] = fmaf(w0, f0.y, acc[2 * k + 1]);
            acc[2 * k]     = fmaf(w1, f1.x, acc[2 * k]);
            acc[2 * k + 1] = fmaf(w1, f1.y, acc[2 * k + 1]);
        }
    }
    if (p < pend) {
        int c0 = col[p];
        uint4 r0 = *reinterpret_cast<const uint4*>(&h[(size_t)c0 * 64 + fl]);
        float w0 = dinv[c0];
        const unsigned* u0 = &r0.x;
#pragma unroll
        for (int k = 0; k < 4; ++k) {
            float2 f0 = __half22float2(*reinterpret_cast<const __half2*>(&u0[k]));
            acc[2 * k]     = fmaf(w0, f0.x, acc[2 * k]);
            acc[2 * k + 1] = fmaf(w0, f0.y, acc[2 * k + 1]);
        }
    }
#pragma unroll
    for (int j = 0; j < 8; ++j) {
        acc[j] += __shfl_xor(acc[j], 8, 64);
        acc[j] += __shfl_xor(acc[j], 16, 64);
        acc[j] += __shfl_xor(acc[j], 32, 64);
    }
    if (g == 0) {                     // lanes 0..7 own the epilogue
        float di = dinv[node];
        uint4 sv = *reinterpret_cast<const uint4*>(&h[(size_t)node * 64 + fl]);
        const unsigned* su = &sv.x;
        float v[8];
#pragma unroll
        for (int k = 0; k < 4; ++k) {
            float2 f = __half22float2(*reinterpret_cast<const __half2*>(&su[k]));
            v[2 * k]     = fmaf(di, f.x, acc[2 * k]) * di;
            v[2 * k + 1] = fmaf(di, f.y, acc[2 * k + 1]) * di;
        }
        if (bias) {
            float4 b0 = *reinterpret_cast<const float4*>(&bias[fl]);
            float4 b1 = *reinterpret_cast<const float4*>(&bias[fl + 4]);
            v[0] += b0.x; v[1] += b0.y; v[2] += b0.z; v[3] += b0.w;
            v[4] += b1.x; v[5] += b1.y; v[6] += b1.z; v[7] += b1.w;
        }
        if (relu) {
#pragma unroll
            for (int j = 0; j < 8; ++j) v[j] = fmaxf(v[j], 0.f);
        }
        if (out_half) {
            __half hv[8];
#pragma unroll
            for (int j = 0; j < 8; ++j) hv[j] = __float2half(v[j]);
            *reinterpret_cast<uint4*>(&((__half*)out)[(size_t)node * 64 + fl]) =
                *reinterpret_cast<const uint4*>(hv);
        } else {
            float* fo = (float*)out;
            *reinterpret_cast<float4*>(&fo[(size_t)node * 64 + fl]) =
                make_float4(v[0], v[1], v[2], v[3]);
            *reinterpret_cast<float4*>(&fo[(size_t)node * 64 + fl + 4]) =
                make_float4(v[4], v[5], v[6], v[7]);
        }
    }
}

// ---------------- GEMM2: [M,64] @ [64,128] + b -> [M,128] ----------------
__global__ __launch_bounds__(256) void gemm2_kernel(const float* __restrict__ A,
                                                    const float* __restrict__ W,
                                                    const float* __restrict__ bias,
                                                    float* __restrict__ out, int M) {
    __shared__ float as[64][65];
    __shared__ float ws[64][128];
    int tid = threadIdx.x;
    int bm = blockIdx.x * 64;
    int ty = tid >> 4, tx = tid & 15;
#pragma unroll
    for (int i = 0; i < 4; ++i) {
        int lin = (tid << 2) + i;
        int r = lin >> 4;
        int c = (lin & 15) << 2;
        float4 v = make_float4(0.f, 0.f, 0.f, 0.f);
        int gr = bm + r;
        if (gr < M) v = *reinterpret_cast<const float4*>(&A[(size_t)gr * 64 + c]);
        as[r][c] = v.x; as[r][c + 1] = v.y; as[r][c + 2] = v.z; as[r][c + 3] = v.w;
    }
#pragma unroll
    for (int i = 0; i < 8; ++i) {
        int lin = tid + (i << 8);
        int r = lin >> 5;
        int c = (lin & 31) << 2;
        *reinterpret_cast<float4*>(&ws[r][c]) =
            *reinterpret_cast<const float4*>(&W[(size_t)r * 128 + c]);
    }
    __syncthreads();
    float acc[4][8] = {};
#pragma unroll 8
    for (int kk = 0; kk < 64; ++kk) {
        float a[4];
#pragma unroll
        for (int i = 0; i < 4; ++i) a[i] = as[ty * 4 + i][kk];
        float b[8];
        float4 b0 = *reinterpret_cast<const float4*>(&ws[kk][tx * 8]);
        float4 b1 = *reinterpret_cast<const float4*>(&ws[kk][tx * 8 + 4]);
        b[0] = b0.x; b[1] = b0.y; b[2] = b0.z; b[3] = b0.w;
        b[4] = b1.x; b[5] = b1.y; b[6] = b1.z; b[7] = b1.w;
#pragma unroll
        for (int i = 0; i < 4; ++i)
#pragma unroll
            for (int j = 0; j < 8; ++j)
                acc[i][j] = fmaf(a[i], b[j], acc[i][j]);
    }
#pragma unroll
    for (int i = 0; i < 4; ++i) {
        int gr = bm + ty * 4 + i;
        if (gr >= M) continue;
#pragma unroll
        for (int jv = 0; jv < 2; ++jv) {
            int cbase = tx * 8 + jv * 4;
            float4 o;
            o.x = acc[i][jv * 4 + 0] + bias[cbase + 0];
            o.y = acc[i][jv * 4 + 1] + bias[cbase + 1];
            o.z = acc[i][jv * 4 + 2] + bias[cbase + 2];
            o.w = acc[i][jv * 4 + 3] + bias[cbase + 3];
            *reinterpret_cast<float4*>(&out[(size_t)gr * 128 + cbase]) = o;
        }
    }
}

extern "C" void kernel_launch(void* const* d_in, const int* in_sizes, int n_in,
                              void* d_out, int out_size, void* d_ws, size_t ws_size,
                              hipStream_t stream) {
    const float* x  = (const float*)d_in[0];
    const int*   ei = (const int*)d_in[1];
    const float* W1 = (const float*)d_in[2];
    const float* b1 = (const float*)d_in[3];
    const float* W2 = (const float*)d_in[4];
    const float* b2 = (const float*)d_in[5];
    float* out = (float*)d_out;
    const int n = NNODES;
    const int E = in_sizes[1] / 2;
    const int CE = (E + NB_CHUNK - 1) / NB_CHUNK;

    char* w = (char*)d_ws;
    auto alloc = [&](size_t bytes) {
        char* p = w;
        w += (bytes + 255) & ~(size_t)255;
        return p;
    };
    int*    flag   = (int*)   alloc(4);
    int*    counts = (int*)   alloc((size_t)NC * 4);
    int*    cbase  = (int*)   alloc((size_t)(NC + 1) * 4);
    int*    indeg  = (int*)   alloc((size_t)n * 4);
    float*  dinv   = (float*) alloc((size_t)n * 4);
    int*    ptr    = (int*)   alloc((size_t)(n + 1) * 4);
    int*    bsum   = (int*)   alloc(128 * 4);
    int*    boff   = (int*)   alloc(128 * 4);
    int*    cw     = (int*)   alloc((size_t)E * 4);
    int*    col    = (int*)   alloc((size_t)E * 4);
    __half* H1     = (__half*)alloc((size_t)n * 64 * 2);
    __half* h1     = (__half*)alloc((size_t)n * 64 * 2);
    float*  A2     = (float*) alloc((size_t)n * 64 * 4);

    int sbC = (NC + SCAN_ELEMS - 1) / SCAN_ELEMS;   // 98
    int sbN = (n  + SCAN_ELEMS - 1) / SCAN_ELEMS;   // 98

    detect_kernel<<<1, 128, 0, stream>>>(ei, flag);
    count_kernel<<<NB_CHUNK, 256, 0, stream>>>(ei, counts, E, CE, flag);
    scan_partial_kernel<<<sbC, 256, 0, stream>>>(counts, bsum, NC);
    scan_partials_kernel<<<1, 128, 0, stream>>>(bsum, boff, &cbase[NC], sbC);
    scan_write_kernel<<<sbC, 256, 0, stream>>>(counts, boff, cbase, NC);
    scatter_kernel<<<NB_CHUNK, 256, 0, stream>>>(ei, cbase, cw, E, CE, flag);
    histdeg_kernel<<<NBUCK, 256, 0, stream>>>(cw, cbase, indeg, dinv, n);
    scan_partial_kernel<<<sbN, 256, 0, stream>>>(indeg, bsum, n);
    scan_partials_kernel<<<1, 128, 0, stream>>>(bsum, boff, &ptr[n], sbN);
    scan_write_kernel<<<sbN, 256, 0, stream>>>(indeg, boff, ptr, n);
    fillcol_kernel<<<NBUCK, 256, 0, stream>>>(cw, cbase, ptr, col, n);

    gemm1_kernel<<<(n + 127) / 128, 128, 0, stream>>>(x, W1, H1, n);
    aggregate_kernel<<<(n + 3) / 4, 256, 0, stream>>>(H1, ptr, col, dinv, b1, h1, n, 1, 1);
    aggregate_kernel<<<(n + 3) / 4, 256, 0, stream>>>(h1, ptr, col, dinv, nullptr, A2, n, 0, 0);
    gemm2_kernel<<<(n + 63) / 64, 256, 0, stream>>>(A2, W2, b2, out, n);
}

// Round 12
// 207.915 us; speedup vs baseline: 1.2130x; 1.2068x over previous
//
#include <hip/hip_runtime.h>
#include <hip/hip_fp16.h>

#define NNODES 100000
#define NBUCK 391                 // ceil(100000/256) buckets of 256 nodes (dst>>8)
#define NB_CHUNK 256              // edge chunks for counting sort
#define NC (NBUCK * NB_CHUNK)     // count-matrix size = 100096
#define SCAN_ELEMS 1024           // elements per scan block (256 threads x 4)

typedef _Float16 f16x8 __attribute__((ext_vector_type(8)));
typedef float    f32x4 __attribute__((ext_vector_type(4)));

// ---------------- edge dtype sniffer (int64 vs int32) ----------------
__global__ void detect_kernel(const int* __restrict__ raw, int* __restrict__ flag) {
    __shared__ int cnt;
    if (threadIdx.x == 0) cnt = 0;
    __syncthreads();
    if (threadIdx.x < 100) {
        if (raw[2 * threadIdx.x + 1] == 0) atomicAdd(&cnt, 1);
    }
    __syncthreads();
    if (threadIdx.x == 0) *flag = (cnt > 50) ? 1 : 0;
}

// ---------------- counting sort pass 1: per-chunk bucket histogram ----------------
__global__ __launch_bounds__(256) void count_kernel(const int* __restrict__ raw,
                                                    int* __restrict__ counts,
                                                    int E, int CE, const int* __restrict__ flag) {
    __shared__ int hist[NBUCK];
    for (int i = threadIdx.x; i < NBUCK; i += 256) hist[i] = 0;
    __syncthreads();
    int b = blockIdx.x;
    int isI64 = *flag;
    int beg = b * CE;
    int end = beg + CE; if (end > E) end = E;
    for (int e = beg + (int)threadIdx.x; e < end; e += 256) {
        int d = isI64 ? raw[2 * E + 2 * e] : raw[E + e];
        atomicAdd(&hist[d >> 8], 1);              // LDS atomic
    }
    __syncthreads();
    for (int k = threadIdx.x; k < NBUCK; k += 256)
        counts[k * NB_CHUNK + b] = hist[k];       // bucket-major for linear scan
}

// ---------------- device-wide exclusive scan (generic) ----------------
__global__ __launch_bounds__(256) void scan_partial_kernel(const int* __restrict__ in,
                                                           int* __restrict__ bsum, int n) {
    int base = blockIdx.x * SCAN_ELEMS + threadIdx.x * 4;
    int s = 0;
    if (base + 3 < n) {
        int4 v = *reinterpret_cast<const int4*>(&in[base]);
        s = v.x + v.y + v.z + v.w;
    } else {
        for (int i = base; i < n && i < base + 4; ++i) s += in[i];
    }
#pragma unroll
    for (int d = 32; d; d >>= 1) s += __shfl_down(s, d, 64);
    __shared__ int ws[4];
    int wid = threadIdx.x >> 6;
    if ((threadIdx.x & 63) == 0) ws[wid] = s;
    __syncthreads();
    if (threadIdx.x == 0) bsum[blockIdx.x] = ws[0] + ws[1] + ws[2] + ws[3];
}

__global__ void scan_partials_kernel(const int* __restrict__ bsum, int* __restrict__ boff,
                                     int* __restrict__ total_out, int nb) {
    __shared__ int s[128];
    int t = threadIdx.x;
    s[t] = (t < nb) ? bsum[t] : 0;
    __syncthreads();
    for (int d = 1; d < 128; d <<= 1) {
        int v = (t >= d) ? s[t - d] : 0;
        __syncthreads();
        s[t] += v;
        __syncthreads();
    }
    if (t < nb) boff[t] = (t == 0) ? 0 : s[t - 1];
    if (t == 127) *total_out = s[127];
}

__global__ __launch_bounds__(256) void scan_write_kernel(const int* __restrict__ in,
                                                         const int* __restrict__ boff,
                                                         int* __restrict__ outp, int n) {
    __shared__ int ts[256];
    int base = blockIdx.x * SCAN_ELEMS + threadIdx.x * 4;
    int v0 = 0, v1 = 0, v2 = 0, v3 = 0;
    if (base + 3 < n) {
        int4 v = *reinterpret_cast<const int4*>(&in[base]);
        v0 = v.x; v1 = v.y; v2 = v.z; v3 = v.w;
    } else {
        if (base < n)     v0 = in[base];
        if (base + 1 < n) v1 = in[base + 1];
        if (base + 2 < n) v2 = in[base + 2];
    }
    ts[threadIdx.x] = v0 + v1 + v2 + v3;
    __syncthreads();
    for (int d = 1; d < 256; d <<= 1) {
        int t = (threadIdx.x >= d) ? ts[threadIdx.x - d] : 0;
        __syncthreads();
        ts[threadIdx.x] += t;
        __syncthreads();
    }
    int run = boff[blockIdx.x] + ((threadIdx.x == 0) ? 0 : ts[threadIdx.x - 1]);
    if (base < n)     { outp[base] = run;     run += v0; }
    if (base + 1 < n) { outp[base + 1] = run; run += v1; }
    if (base + 2 < n) { outp[base + 2] = run; run += v2; }
    if (base + 3 < n) { outp[base + 3] = run; }
}

// ---------------- counting sort pass 2: scatter (packed: src | (d&255)<<24) ----------------
__global__ __launch_bounds__(256) void scatter_kernel(const int* __restrict__ raw,
                                                      const int* __restrict__ cbase,
                                                      int* __restrict__ cw,
                                                      int E, int CE, const int* __restrict__ flag) {
    __shared__ int cur[NBUCK];
    int b = blockIdx.x;
    for (int k = threadIdx.x; k < NBUCK; k += 256)
        cur[k] = cbase[k * NB_CHUNK + b];
    __syncthreads();
    int isI64 = *flag;
    int beg = b * CE;
    int end = beg + CE; if (end > E) end = E;
    for (int e = beg + (int)threadIdx.x; e < end; e += 256) {
        int s, d;
        if (isI64) { s = raw[2 * e]; d = raw[2 * E + 2 * e]; }
        else       { s = raw[e];     d = raw[E + e]; }
        int pos = atomicAdd(&cur[d >> 8], 1);     // LDS atomic
        cw[pos] = s | ((d & 255) << 24);          // single-CU contiguous run per bucket
    }
}

// ---------------- per-bucket degree histogram + dinv (coalesced, atomic-free) ----------------
__global__ __launch_bounds__(256) void histdeg_kernel(const int* __restrict__ cw,
                                                      const int* __restrict__ cbase,
                                                      int* __restrict__ indeg,
                                                      float* __restrict__ dinv, int n) {
    __shared__ int hist[256];
    hist[threadIdx.x] = 0;
    __syncthreads();
    int k = blockIdx.x;
    int beg = cbase[k * NB_CHUNK];
    int end = cbase[(k + 1) * NB_CHUNK];
    for (int e = beg + (int)threadIdx.x; e < end; e += 256)
        atomicAdd(&hist[(cw[e] >> 24) & 255], 1); // LDS atomic
    __syncthreads();
    int i = (k << 8) + threadIdx.x;
    if (i < n) {
        int dg = hist[threadIdx.x];
        indeg[i] = dg;
        dinv[i] = rsqrtf((float)(dg + 1));        // +1 self loop; always > 0
    }
}

// ---------------- per-bucket CSR col fill (LDS cursors, single-CU-owned window) ----------------
__global__ __launch_bounds__(256) void fillcol_kernel(const int* __restrict__ cw,
                                                      const int* __restrict__ cbase,
                                                      const int* __restrict__ ptr,
                                                      int* __restrict__ col, int n) {
    __shared__ int cur[256];
    int k = blockIdx.x;
    int i = (k << 8) + threadIdx.x;
    cur[threadIdx.x] = (i < n) ? ptr[i] : 0;
    __syncthreads();
    int beg = cbase[k * NB_CHUNK];
    int end = cbase[(k + 1) * NB_CHUNK];
    for (int e = beg + (int)threadIdx.x; e < end; e += 256) {
        int v = cw[e];
        int pos = atomicAdd(&cur[(v >> 24) & 255], 1); // LDS atomic; pos is global index
        col[pos] = v & 0x00FFFFFF;
    }
}

// ---------------- W1 -> MFMA B-fragment order, fp16 (one-time, 16384 elems) ----------------
// wf[flat], flat = ((kc*4+nb)*64 + lane)*8 + j  <=  W[kc*32 + (lane>>4)*8 + j][nb*16 + (lane&15)]
__global__ void wfrag_kernel(const float* __restrict__ W, __half* __restrict__ wf) {
    int flat = blockIdx.x * 256 + threadIdx.x;    // 64 blocks x 256 = 16384
    int j  = flat & 7;
    int l  = (flat >> 3) & 63;
    int nb = (flat >> 9) & 3;
    int kc = flat >> 11;
    int k  = kc * 32 + ((l >> 4) << 3) + j;
    int nc = nb * 16 + (l & 15);
    wf[flat] = __float2half(W[k * 64 + nc]);
}

// ---------------- GEMM1 via MFMA: [M,256]fp32 @ [256,64] -> fp16 [M,64] ----------------
// Block = 4 waves x 16 rows (BM=64). x staged to LDS as fp16 [64][264] (rows 16B-
// aligned, <=2-way banks). a-frag = 1 ds_read_b128; b-frags stream from the
// fragment-ordered global table (1KB coalesced dwordx4 per instr, L2-hot).
// v_mfma_f32_16x16x32_f16: A row=l&15, k=(l>>4)*8+j; B col=l&15, same k;
// C col=l&15, row=(l>>4)*4+r.
__global__ __launch_bounds__(256) void gemm1_kernel(const float* __restrict__ x,
                                                    const __half* __restrict__ wf,
                                                    __half* __restrict__ H, int M) {
    __shared__ __half xs[64][264];
    int tid = threadIdx.x;
    int bm = blockIdx.x * 64;
    const float4* x4 = reinterpret_cast<const float4*>(x);
    // stage x tile: 64 rows x 64 float4 = 4096 float4, 16 per thread
#pragma unroll
    for (int i = 0; i < 16; ++i) {
        int lin = i * 256 + tid;
        int row = lin >> 6;
        int c4  = lin & 63;
        int gr = bm + row; if (gr >= M) gr = M - 1;
        float4 v = x4[(size_t)gr * 64 + c4];
        __half* dst = &xs[row][c4 * 4];
        dst[0] = __float2half(v.x); dst[1] = __float2half(v.y);
        dst[2] = __float2half(v.z); dst[3] = __float2half(v.w);
    }
    __syncthreads();
    int w = tid >> 6;          // wave 0..3 -> rows bm+w*16 .. +15
    int l = tid & 63;
    int lrow = l & 15;
    int lk   = l >> 4;
    const f16x8* wf8 = reinterpret_cast<const f16x8*>(wf);
    f32x4 acc[4] = {};
#pragma unroll
    for (int kc = 0; kc < 8; ++kc) {
        f16x8 a = *reinterpret_cast<const f16x8*>(&xs[w * 16 + lrow][kc * 32 + lk * 8]);
#pragma unroll
        for (int nb = 0; nb < 4; ++nb) {
            f16x8 b = wf8[(kc * 4 + nb) * 64 + l];
            acc[nb] = __builtin_amdgcn_mfma_f32_16x16x32_f16(a, b, acc[nb], 0, 0, 0);
        }
    }
#pragma unroll
    for (int nb = 0; nb < 4; ++nb)
#pragma unroll
        for (int r = 0; r < 4; ++r) {
            int row = bm + w * 16 + lk * 4 + r;
            if (row < M) H[(size_t)row * 64 + nb * 16 + lrow] = __float2half(acc[nb][r]);
        }
}

// ---------------- aggregation: fp16 gathers, 8-lane groups (8 edges/instr) ----------------
__global__ __launch_bounds__(256) void aggregate_kernel(const __half* __restrict__ h,
                                                        const int* __restrict__ ptr,
                                                        const int* __restrict__ col,
                                                        const float* __restrict__ dinv,
                                                        const float* __restrict__ bias,
                                                        void* __restrict__ out, int n,
                                                        int relu, int out_half) {
    int node = (blockIdx.x << 2) + (threadIdx.x >> 6);
    if (node >= n) return;
    int lane = threadIdx.x & 63;
    int g  = lane >> 3;               // edge-group 0..7
    int fl = (lane & 7) << 3;         // feature base: 0,8,...,56
    float acc[8] = {};
    int pend = ptr[node + 1];
    int p = ptr[node] + g;
    for (; p + 8 < pend; p += 16) {   // unroll 2: 16 edges in flight per wave
        int c0 = col[p];
        int c1 = col[p + 8];
        uint4 r0 = *reinterpret_cast<const uint4*>(&h[(size_t)c0 * 64 + fl]);
        uint4 r1 = *reinterpret_cast<const uint4*>(&h[(size_t)c1 * 64 + fl]);
        float w0 = dinv[c0], w1 = dinv[c1];
        const unsigned* u0 = &r0.x;
        const unsigned* u1 = &r1.x;
#pragma unroll
        for (int k = 0; k < 4; ++k) {
            float2 f0 = __half22float2(*reinterpret_cast<const __half2*>(&u0[k]));
            float2 f1 = __half22float2(*reinterpret_cast<const __half2*>(&u1[k]));
            acc[2 * k]     = fmaf(w0, f0.x, acc[2 * k]);
            acc[2 * k + 1] = fmaf(w0, f0.y, acc[2 * k + 1]);
            acc[2 * k]     = fmaf(w1, f1.x, acc[2 * k]);
            acc[2 * k + 1] = fmaf(w1, f1.y, acc[2 * k + 1]);
        }
    }
    if (p < pend) {
        int c0 = col[p];
        uint4 r0 = *reinterpret_cast<const uint4*>(&h[(size_t)c0 * 64 + fl]);
        float w0 = dinv[c0];
        const unsigned* u0 = &r0.x;
#pragma unroll
        for (int k = 0; k < 4; ++k) {
            float2 f0 = __half22float2(*reinterpret_cast<const __half2*>(&u0[k]));
            acc[2 * k]     = fmaf(w0, f0.x, acc[2 * k]);
            acc[2 * k + 1] = fmaf(w0, f0.y, acc[2 * k + 1]);
        }
    }
#pragma unroll
    for (int j = 0; j < 8; ++j) {
        acc[j] += __shfl_xor(acc[j], 8, 64);
        acc[j] += __shfl_xor(acc[j], 16, 64);
        acc[j] += __shfl_xor(acc[j], 32, 64);
    }
    if (g == 0) {                     // lanes 0..7 own the epilogue
        float di = dinv[node];
        uint4 sv = *reinterpret_cast<const uint4*>(&h[(size_t)node * 64 + fl]);
        const unsigned* su = &sv.x;
        float v[8];
#pragma unroll
        for (int k = 0; k < 4; ++k) {
            float2 f = __half22float2(*reinterpret_cast<const __half2*>(&su[k]));
            v[2 * k]     = fmaf(di, f.x, acc[2 * k]) * di;
            v[2 * k + 1] = fmaf(di, f.y, acc[2 * k + 1]) * di;
        }
        if (bias) {
            float4 b0 = *reinterpret_cast<const float4*>(&bias[fl]);
            float4 b1 = *reinterpret_cast<const float4*>(&bias[fl + 4]);
            v[0] += b0.x; v[1] += b0.y; v[2] += b0.z; v[3] += b0.w;
            v[4] += b1.x; v[5] += b1.y; v[6] += b1.z; v[7] += b1.w;
        }
        if (relu) {
#pragma unroll
            for (int j = 0; j < 8; ++j) v[j] = fmaxf(v[j], 0.f);
        }
        if (out_half) {
            __half hv[8];
#pragma unroll
            for (int j = 0; j < 8; ++j) hv[j] = __float2half(v[j]);
            *reinterpret_cast<uint4*>(&((__half*)out)[(size_t)node * 64 + fl]) =
                *reinterpret_cast<const uint4*>(hv);
        } else {
            float* fo = (float*)out;
            *reinterpret_cast<float4*>(&fo[(size_t)node * 64 + fl]) =
                make_float4(v[0], v[1], v[2], v[3]);
            *reinterpret_cast<float4*>(&fo[(size_t)node * 64 + fl + 4]) =
                make_float4(v[4], v[5], v[6], v[7]);
        }
    }
}

// ---------------- GEMM2: [M,64] @ [64,128] + b -> [M,128] ----------------
__global__ __launch_bounds__(256) void gemm2_kernel(const float* __restrict__ A,
                                                    const float* __restrict__ W,
                                                    const float* __restrict__ bias,
                                                    float* __restrict__ out, int M) {
    __shared__ float as[64][65];
    __shared__ float ws[64][128];
    int tid = threadIdx.x;
    int bm = blockIdx.x * 64;
    int ty = tid >> 4, tx = tid & 15;
#pragma unroll
    for (int i = 0; i < 4; ++i) {
        int lin = (tid << 2) + i;
        int r = lin >> 4;
        int c = (lin & 15) << 2;
        float4 v = make_float4(0.f, 0.f, 0.f, 0.f);
        int gr = bm + r;
        if (gr < M) v = *reinterpret_cast<const float4*>(&A[(size_t)gr * 64 + c]);
        as[r][c] = v.x; as[r][c + 1] = v.y; as[r][c + 2] = v.z; as[r][c + 3] = v.w;
    }
#pragma unroll
    for (int i = 0; i < 8; ++i) {
        int lin = tid + (i << 8);
        int r = lin >> 5;
        int c = (lin & 31) << 2;
        *reinterpret_cast<float4*>(&ws[r][c]) =
            *reinterpret_cast<const float4*>(&W[(size_t)r * 128 + c]);
    }
    __syncthreads();
    float acc[4][8] = {};
#pragma unroll 8
    for (int kk = 0; kk < 64; ++kk) {
        float a[4];
#pragma unroll
        for (int i = 0; i < 4; ++i) a[i] = as[ty * 4 + i][kk];
        float b[8];
        float4 b0 = *reinterpret_cast<const float4*>(&ws[kk][tx * 8]);
        float4 b1 = *reinterpret_cast<const float4*>(&ws[kk][tx * 8 + 4]);
        b[0] = b0.x; b[1] = b0.y; b[2] = b0.z; b[3] = b0.w;
        b[4] = b1.x; b[5] = b1.y; b[6] = b1.z; b[7] = b1.w;
#pragma unroll
        for (int i = 0; i < 4; ++i)
#pragma unroll
            for (int j = 0; j < 8; ++j)
                acc[i][j] = fmaf(a[i], b[j], acc[i][j]);
    }
#pragma unroll
    for (int i = 0; i < 4; ++i) {
        int gr = bm + ty * 4 + i;
        if (gr >= M) continue;
#pragma unroll
        for (int jv = 0; jv < 2; ++jv) {
            int cbase = tx * 8 + jv * 4;
            float4 o;
            o.x = acc[i][jv * 4 + 0] + bias[cbase + 0];
            o.y = acc[i][jv * 4 + 1] + bias[cbase + 1];
            o.z = acc[i][jv * 4 + 2] + bias[cbase + 2];
            o.w = acc[i][jv * 4 + 3] + bias[cbase + 3];
            *reinterpret_cast<float4*>(&out[(size_t)gr * 128 + cbase]) = o;
        }
    }
}

extern "C" void kernel_launch(void* const* d_in, const int* in_sizes, int n_in,
                              void* d_out, int out_size, void* d_ws, size_t ws_size,
                              hipStream_t stream) {
    const float* x  = (const float*)d_in[0];
    const int*   ei = (const int*)d_in[1];
    const float* W1 = (const float*)d_in[2];
    const float* b1 = (const float*)d_in[3];
    const float* W2 = (const float*)d_in[4];
    const float* b2 = (const float*)d_in[5];
    float* out = (float*)d_out;
    const int n = NNODES;
    const int E = in_sizes[1] / 2;
    const int CE = (E + NB_CHUNK - 1) / NB_CHUNK;

    char* w = (char*)d_ws;
    auto alloc = [&](size_t bytes) {
        char* p = w;
        w += (bytes + 255) & ~(size_t)255;
        return p;
    };
    int*    flag   = (int*)   alloc(4);
    int*    counts = (int*)   alloc((size_t)NC * 4);
    int*    cbase  = (int*)   alloc((size_t)(NC + 1) * 4);
    int*    indeg  = (int*)   alloc((size_t)n * 4);
    float*  dinv   = (float*) alloc((size_t)n * 4);
    int*    ptr    = (int*)   alloc((size_t)(n + 1) * 4);
    int*    bsum   = (int*)   alloc(128 * 4);
    int*    boff   = (int*)   alloc(128 * 4);
    int*    cw     = (int*)   alloc((size_t)E * 4);
    int*    col    = (int*)   alloc((size_t)E * 4);
    __half* wfrag  = (__half*)alloc(16384 * 2);
    __half* H1     = (__half*)alloc((size_t)n * 64 * 2);
    __half* h1     = (__half*)alloc((size_t)n * 64 * 2);
    float*  A2     = (float*) alloc((size_t)n * 64 * 4);

    int sbC = (NC + SCAN_ELEMS - 1) / SCAN_ELEMS;   // 98
    int sbN = (n  + SCAN_ELEMS - 1) / SCAN_ELEMS;   // 98

    detect_kernel<<<1, 128, 0, stream>>>(ei, flag);
    wfrag_kernel<<<64, 256, 0, stream>>>(W1, wfrag);
    count_kernel<<<NB_CHUNK, 256, 0, stream>>>(ei, counts, E, CE, flag);
    scan_partial_kernel<<<sbC, 256, 0, stream>>>(counts, bsum, NC);
    scan_partials_kernel<<<1, 128, 0, stream>>>(bsum, boff, &cbase[NC], sbC);
    scan_write_kernel<<<sbC, 256, 0, stream>>>(counts, boff, cbase, NC);
    scatter_kernel<<<NB_CHUNK, 256, 0, stream>>>(ei, cbase, cw, E, CE, flag);
    histdeg_kernel<<<NBUCK, 256, 0, stream>>>(cw, cbase, indeg, dinv, n);
    scan_partial_kernel<<<sbN, 256, 0, stream>>>(indeg, bsum, n);
    scan_partials_kernel<<<1, 128, 0, stream>>>(bsum, boff, &ptr[n], sbN);
    scan_write_kernel<<<sbN, 256, 0, stream>>>(indeg, boff, ptr, n);
    fillcol_kernel<<<NBUCK, 256, 0, stream>>>(cw, cbase, ptr, col, n);

    gemm1_kernel<<<(n + 63) / 64, 256, 0, stream>>>(x, wfrag, H1, n);
    aggregate_kernel<<<(n + 3) / 4, 256, 0, stream>>>(H1, ptr, col, dinv, b1, h1, n, 1, 1);
    aggregate_kernel<<<(n + 3) / 4, 256, 0, stream>>>(h1, ptr, col, dinv, nullptr, A2, n, 0, 0);
    gemm2_kernel<<<(n + 63) / 64, 256, 0, stream>>>(A2, W2, b2, out, n);
}

// Round 13
// 198.176 us; speedup vs baseline: 1.2726x; 1.0491x over previous
//
#include <hip/hip_runtime.h>
#include <hip/hip_fp16.h>

#define NNODES 100000
#define NBUCK 391                 // ceil(100000/256) buckets of 256 nodes (dst>>8)
#define NB_CHUNK 256              // edge chunks for counting sort
#define NC (NBUCK * NB_CHUNK)     // count-matrix size = 100096
#define SCAN_ELEMS 1024           // elements per scan block (256 threads x 4)

typedef _Float16 f16x8 __attribute__((ext_vector_type(8)));
typedef float    f32x4 __attribute__((ext_vector_type(4)));

// ---------------- edge dtype sniffer (int64 vs int32) ----------------
__global__ void detect_kernel(const int* __restrict__ raw, int* __restrict__ flag) {
    __shared__ int cnt;
    if (threadIdx.x == 0) cnt = 0;
    __syncthreads();
    if (threadIdx.x < 100) {
        if (raw[2 * threadIdx.x + 1] == 0) atomicAdd(&cnt, 1);
    }
    __syncthreads();
    if (threadIdx.x == 0) *flag = (cnt > 50) ? 1 : 0;
}

// ---------------- fused convert + per-chunk bucket histogram ----------------
// Reads raw edges ONCE (int64 or int32), emits compact int32 src/dst arrays and
// the counting-sort chunk histograms. Scatter then streams the 2x smaller arrays.
__global__ __launch_bounds__(256) void convert_count_kernel(const int* __restrict__ raw,
                                                            int* __restrict__ src32,
                                                            int* __restrict__ dst32,
                                                            int* __restrict__ counts,
                                                            int E, int CE,
                                                            const int* __restrict__ flag) {
    __shared__ int hist[NBUCK];
    for (int i = threadIdx.x; i < NBUCK; i += 256) hist[i] = 0;
    __syncthreads();
    int b = blockIdx.x;
    int isI64 = *flag;
    int beg = b * CE;
    int end = beg + CE; if (end > E) end = E;
    for (int e = beg + (int)threadIdx.x; e < end; e += 256) {
        int s, d;
        if (isI64) { s = raw[2 * e]; d = raw[2 * E + 2 * e]; }
        else       { s = raw[e];     d = raw[E + e]; }
        src32[e] = s;
        dst32[e] = d;
        atomicAdd(&hist[d >> 8], 1);              // LDS atomic
    }
    __syncthreads();
    for (int k = threadIdx.x; k < NBUCK; k += 256)
        counts[k * NB_CHUNK + b] = hist[k];       // bucket-major for linear scan
}

// ---------------- device-wide exclusive scan (generic) ----------------
__global__ __launch_bounds__(256) void scan_partial_kernel(const int* __restrict__ in,
                                                           int* __restrict__ bsum, int n) {
    int base = blockIdx.x * SCAN_ELEMS + threadIdx.x * 4;
    int s = 0;
    if (base + 3 < n) {
        int4 v = *reinterpret_cast<const int4*>(&in[base]);
        s = v.x + v.y + v.z + v.w;
    } else {
        for (int i = base; i < n && i < base + 4; ++i) s += in[i];
    }
#pragma unroll
    for (int d = 32; d; d >>= 1) s += __shfl_down(s, d, 64);
    __shared__ int ws[4];
    int wid = threadIdx.x >> 6;
    if ((threadIdx.x & 63) == 0) ws[wid] = s;
    __syncthreads();
    if (threadIdx.x == 0) bsum[blockIdx.x] = ws[0] + ws[1] + ws[2] + ws[3];
}

__global__ void scan_partials_kernel(const int* __restrict__ bsum, int* __restrict__ boff,
                                     int* __restrict__ total_out, int nb) {
    __shared__ int s[128];
    int t = threadIdx.x;
    s[t] = (t < nb) ? bsum[t] : 0;
    __syncthreads();
    for (int d = 1; d < 128; d <<= 1) {
        int v = (t >= d) ? s[t - d] : 0;
        __syncthreads();
        s[t] += v;
        __syncthreads();
    }
    if (t < nb) boff[t] = (t == 0) ? 0 : s[t - 1];
    if (t == 127) *total_out = s[127];
}

__global__ __launch_bounds__(256) void scan_write_kernel(const int* __restrict__ in,
                                                         const int* __restrict__ boff,
                                                         int* __restrict__ outp, int n) {
    __shared__ int ts[256];
    int base = blockIdx.x * SCAN_ELEMS + threadIdx.x * 4;
    int v0 = 0, v1 = 0, v2 = 0, v3 = 0;
    if (base + 3 < n) {
        int4 v = *reinterpret_cast<const int4*>(&in[base]);
        v0 = v.x; v1 = v.y; v2 = v.z; v3 = v.w;
    } else {
        if (base < n)     v0 = in[base];
        if (base + 1 < n) v1 = in[base + 1];
        if (base + 2 < n) v2 = in[base + 2];
    }
    ts[threadIdx.x] = v0 + v1 + v2 + v3;
    __syncthreads();
    for (int d = 1; d < 256; d <<= 1) {
        int t = (threadIdx.x >= d) ? ts[threadIdx.x - d] : 0;
        __syncthreads();
        ts[threadIdx.x] += t;
        __syncthreads();
    }
    int run = boff[blockIdx.x] + ((threadIdx.x == 0) ? 0 : ts[threadIdx.x - 1]);
    if (base < n)     { outp[base] = run;     run += v0; }
    if (base + 1 < n) { outp[base + 1] = run; run += v1; }
    if (base + 2 < n) { outp[base + 2] = run; run += v2; }
    if (base + 3 < n) { outp[base + 3] = run; }
}

// ---------------- counting sort pass 2: scatter (packed: src | (d&255)<<24) ----------------
__global__ __launch_bounds__(256) void scatter_kernel(const int* __restrict__ src32,
                                                      const int* __restrict__ dst32,
                                                      const int* __restrict__ cbase,
                                                      int* __restrict__ cw,
                                                      int E, int CE) {
    __shared__ int cur[NBUCK];
    int b = blockIdx.x;
    for (int k = threadIdx.x; k < NBUCK; k += 256)
        cur[k] = cbase[k * NB_CHUNK + b];
    __syncthreads();
    int beg = b * CE;
    int end = beg + CE; if (end > E) end = E;
    for (int e = beg + (int)threadIdx.x; e < end; e += 256) {
        int s = src32[e];
        int d = dst32[e];
        int pos = atomicAdd(&cur[d >> 8], 1);     // LDS atomic
        cw[pos] = s | ((d & 255) << 24);          // single-CU contiguous run per bucket
    }
}

// ---------------- per-bucket degree histogram + dinv (coalesced, atomic-free) ----------------
__global__ __launch_bounds__(256) void histdeg_kernel(const int* __restrict__ cw,
                                                      const int* __restrict__ cbase,
                                                      int* __restrict__ indeg,
                                                      float* __restrict__ dinv, int n) {
    __shared__ int hist[256];
    hist[threadIdx.x] = 0;
    __syncthreads();
    int k = blockIdx.x;
    int beg = cbase[k * NB_CHUNK];
    int end = cbase[(k + 1) * NB_CHUNK];
    for (int e = beg + (int)threadIdx.x; e < end; e += 256)
        atomicAdd(&hist[(cw[e] >> 24) & 255], 1); // LDS atomic
    __syncthreads();
    int i = (k << 8) + threadIdx.x;
    if (i < n) {
        int dg = hist[threadIdx.x];
        indeg[i] = dg;
        dinv[i] = rsqrtf((float)(dg + 1));        // +1 self loop; always > 0
    }
}

// ---------------- per-bucket CSR col fill (LDS cursors, single-CU-owned window) ----------------
__global__ __launch_bounds__(256) void fillcol_kernel(const int* __restrict__ cw,
                                                      const int* __restrict__ cbase,
                                                      const int* __restrict__ ptr,
                                                      int* __restrict__ col, int n) {
    __shared__ int cur[256];
    int k = blockIdx.x;
    int i = (k << 8) + threadIdx.x;
    cur[threadIdx.x] = (i < n) ? ptr[i] : 0;
    __syncthreads();
    int beg = cbase[k * NB_CHUNK];
    int end = cbase[(k + 1) * NB_CHUNK];
    for (int e = beg + (int)threadIdx.x; e < end; e += 256) {
        int v = cw[e];
        int pos = atomicAdd(&cur[(v >> 24) & 255], 1); // LDS atomic; pos is global index
        col[pos] = v & 0x00FFFFFF;
    }
}

// ---------------- W1 -> MFMA B-fragment order, fp16 (one-time, 16384 elems) ----------------
// wf[flat], flat = ((kc*4+nb)*64 + lane)*8 + j  <=  W[kc*32 + (lane>>4)*8 + j][nb*16 + (lane&15)]
__global__ void wfrag_kernel(const float* __restrict__ W, __half* __restrict__ wf) {
    int flat = blockIdx.x * 256 + threadIdx.x;    // 64 blocks x 256 = 16384
    int j  = flat & 7;
    int l  = (flat >> 3) & 63;
    int nb = (flat >> 9) & 3;
    int kc = flat >> 11;
    int k  = kc * 32 + ((l >> 4) << 3) + j;
    int nc = nb * 16 + (l & 15);
    wf[flat] = __float2half(W[k * 64 + nc]);
}

// ---------------- W2 [64,128] -> MFMA B-fragment order, fp16 (8192 elems) ----------------
// wf2[flat], flat = ((kc*8+nb)*64 + lane)*8 + j <= W2[kc*32 + (lane>>4)*8 + j][nb*16 + (lane&15)]
__global__ void wfrag2_kernel(const float* __restrict__ W, __half* __restrict__ wf) {
    int flat = blockIdx.x * 256 + threadIdx.x;    // 32 blocks x 256 = 8192
    int j  = flat & 7;
    int l  = (flat >> 3) & 63;
    int nb = (flat >> 9) & 7;
    int kc = flat >> 12;
    int k  = kc * 32 + ((l >> 4) << 3) + j;
    int nc = nb * 16 + (l & 15);
    wf[flat] = __float2half(W[k * 128 + nc]);
}

// ---------------- GEMM1 via MFMA: [M,256]fp32 @ [256,64] -> fp16 [M,64] ----------------
__global__ __launch_bounds__(256) void gemm1_kernel(const float* __restrict__ x,
                                                    const __half* __restrict__ wf,
                                                    __half* __restrict__ H, int M) {
    __shared__ __half xs[64][264];
    int tid = threadIdx.x;
    int bm = blockIdx.x * 64;
    const float4* x4 = reinterpret_cast<const float4*>(x);
#pragma unroll
    for (int i = 0; i < 16; ++i) {
        int lin = i * 256 + tid;
        int row = lin >> 6;
        int c4  = lin & 63;
        int gr = bm + row; if (gr >= M) gr = M - 1;
        float4 v = x4[(size_t)gr * 64 + c4];
        __half* dst = &xs[row][c4 * 4];
        dst[0] = __float2half(v.x); dst[1] = __float2half(v.y);
        dst[2] = __float2half(v.z); dst[3] = __float2half(v.w);
    }
    __syncthreads();
    int w = tid >> 6;          // wave 0..3 -> rows bm+w*16 .. +15
    int l = tid & 63;
    int lrow = l & 15;
    int lk   = l >> 4;
    const f16x8* wf8 = reinterpret_cast<const f16x8*>(wf);
    f32x4 acc[4] = {};
#pragma unroll
    for (int kc = 0; kc < 8; ++kc) {
        f16x8 a = *reinterpret_cast<const f16x8*>(&xs[w * 16 + lrow][kc * 32 + lk * 8]);
#pragma unroll
        for (int nb = 0; nb < 4; ++nb) {
            f16x8 b = wf8[(kc * 4 + nb) * 64 + l];
            acc[nb] = __builtin_amdgcn_mfma_f32_16x16x32_f16(a, b, acc[nb], 0, 0, 0);
        }
    }
#pragma unroll
    for (int nb = 0; nb < 4; ++nb)
#pragma unroll
        for (int r = 0; r < 4; ++r) {
            int row = bm + w * 16 + lk * 4 + r;
            if (row < M) H[(size_t)row * 64 + nb * 16 + lrow] = __float2half(acc[nb][r]);
        }
}

// ---------------- aggregation: fp16 gathers, 8-lane groups (8 edges/instr) ----------------
__global__ __launch_bounds__(256) void aggregate_kernel(const __half* __restrict__ h,
                                                        const int* __restrict__ ptr,
                                                        const int* __restrict__ col,
                                                        const float* __restrict__ dinv,
                                                        const float* __restrict__ bias,
                                                        void* __restrict__ out, int n,
                                                        int relu, int out_half) {
    int node = (blockIdx.x << 2) + (threadIdx.x >> 6);
    if (node >= n) return;
    int lane = threadIdx.x & 63;
    int g  = lane >> 3;               // edge-group 0..7
    int fl = (lane & 7) << 3;         // feature base: 0,8,...,56
    float acc[8] = {};
    int pend = ptr[node + 1];
    int p = ptr[node] + g;
    for (; p + 8 < pend; p += 16) {   // unroll 2: 16 edges in flight per wave
        int c0 = col[p];
        int c1 = col[p + 8];
        uint4 r0 = *reinterpret_cast<const uint4*>(&h[(size_t)c0 * 64 + fl]);
        uint4 r1 = *reinterpret_cast<const uint4*>(&h[(size_t)c1 * 64 + fl]);
        float w0 = dinv[c0], w1 = dinv[c1];
        const unsigned* u0 = &r0.x;
        const unsigned* u1 = &r1.x;
#pragma unroll
        for (int k = 0; k < 4; ++k) {
            float2 f0 = __half22float2(*reinterpret_cast<const __half2*>(&u0[k]));
            float2 f1 = __half22float2(*reinterpret_cast<const __half2*>(&u1[k]));
            acc[2 * k]     = fmaf(w0, f0.x, acc[2 * k]);
            acc[2 * k + 1] = fmaf(w0, f0.y, acc[2 * k + 1]);
            acc[2 * k]     = fmaf(w1, f1.x, acc[2 * k]);
            acc[2 * k + 1] = fmaf(w1, f1.y, acc[2 * k + 1]);
        }
    }
    if (p < pend) {
        int c0 = col[p];
        uint4 r0 = *reinterpret_cast<const uint4*>(&h[(size_t)c0 * 64 + fl]);
        float w0 = dinv[c0];
        const unsigned* u0 = &r0.x;
#pragma unroll
        for (int k = 0; k < 4; ++k) {
            float2 f0 = __half22float2(*reinterpret_cast<const __half2*>(&u0[k]));
            acc[2 * k]     = fmaf(w0, f0.x, acc[2 * k]);
            acc[2 * k + 1] = fmaf(w0, f0.y, acc[2 * k + 1]);
        }
    }
#pragma unroll
    for (int j = 0; j < 8; ++j) {
        acc[j] += __shfl_xor(acc[j], 8, 64);
        acc[j] += __shfl_xor(acc[j], 16, 64);
        acc[j] += __shfl_xor(acc[j], 32, 64);
    }
    if (g == 0) {                     // lanes 0..7 own the epilogue
        float di = dinv[node];
        uint4 sv = *reinterpret_cast<const uint4*>(&h[(size_t)node * 64 + fl]);
        const unsigned* su = &sv.x;
        float v[8];
#pragma unroll
        for (int k = 0; k < 4; ++k) {
            float2 f = __half22float2(*reinterpret_cast<const __half2*>(&su[k]));
            v[2 * k]     = fmaf(di, f.x, acc[2 * k]) * di;
            v[2 * k + 1] = fmaf(di, f.y, acc[2 * k + 1]) * di;
        }
        if (bias) {
            float4 b0 = *reinterpret_cast<const float4*>(&bias[fl]);
            float4 b1 = *reinterpret_cast<const float4*>(&bias[fl + 4]);
            v[0] += b0.x; v[1] += b0.y; v[2] += b0.z; v[3] += b0.w;
            v[4] += b1.x; v[5] += b1.y; v[6] += b1.z; v[7] += b1.w;
        }
        if (relu) {
#pragma unroll
            for (int j = 0; j < 8; ++j) v[j] = fmaxf(v[j], 0.f);
        }
        if (out_half) {
            __half hv[8];
#pragma unroll
            for (int j = 0; j < 8; ++j) hv[j] = __float2half(v[j]);
            *reinterpret_cast<uint4*>(&((__half*)out)[(size_t)node * 64 + fl]) =
                *reinterpret_cast<const uint4*>(hv);
        } else {
            float* fo = (float*)out;
            *reinterpret_cast<float4*>(&fo[(size_t)node * 64 + fl]) =
                make_float4(v[0], v[1], v[2], v[3]);
            *reinterpret_cast<float4*>(&fo[(size_t)node * 64 + fl + 4]) =
                make_float4(v[4], v[5], v[6], v[7]);
        }
    }
}

// ---------------- GEMM2 via MFMA: fp16 [M,64] @ [64,128] + b -> fp32 [M,128] ----------------
// A-frags straight from global (lane's 16B at row*64 + lk*8, coalesced 16-row
// panels); b-frags from the L2-hot fragment table. 4 waves x 16 rows per block.
__global__ __launch_bounds__(256) void gemm2_kernel(const __half* __restrict__ A,
                                                    const __half* __restrict__ wf,
                                                    const float* __restrict__ bias,
                                                    float* __restrict__ out, int M) {
    int tid = threadIdx.x;
    int w = tid >> 6;
    int l = tid & 63;
    int lrow = l & 15;
    int lk   = l >> 4;
    int base = blockIdx.x * 64 + w * 16;
    int arow = base + lrow; if (arow >= M) arow = M - 1;
    f16x8 a0 = *reinterpret_cast<const f16x8*>(&A[(size_t)arow * 64 + lk * 8]);
    f16x8 a1 = *reinterpret_cast<const f16x8*>(&A[(size_t)arow * 64 + 32 + lk * 8]);
    const f16x8* wf8 = reinterpret_cast<const f16x8*>(wf);
    f32x4 acc[8] = {};
#pragma unroll
    for (int nb = 0; nb < 8; ++nb) {
        acc[nb] = __builtin_amdgcn_mfma_f32_16x16x32_f16(a0, wf8[nb * 64 + l], acc[nb], 0, 0, 0);
        acc[nb] = __builtin_amdgcn_mfma_f32_16x16x32_f16(a1, wf8[(8 + nb) * 64 + l], acc[nb], 0, 0, 0);
    }
#pragma unroll
    for (int nb = 0; nb < 8; ++nb) {
        float bv = bias[nb * 16 + lrow];
#pragma unroll
        for (int r = 0; r < 4; ++r) {
            int row = base + lk * 4 + r;
            if (row < M) out[(size_t)row * 128 + nb * 16 + lrow] = acc[nb][r] + bv;
        }
    }
}

extern "C" void kernel_launch(void* const* d_in, const int* in_sizes, int n_in,
                              void* d_out, int out_size, void* d_ws, size_t ws_size,
                              hipStream_t stream) {
    const float* x  = (const float*)d_in[0];
    const int*   ei = (const int*)d_in[1];
    const float* W1 = (const float*)d_in[2];
    const float* b1 = (const float*)d_in[3];
    const float* W2 = (const float*)d_in[4];
    const float* b2 = (const float*)d_in[5];
    float* out = (float*)d_out;
    const int n = NNODES;
    const int E = in_sizes[1] / 2;
    const int CE = (E + NB_CHUNK - 1) / NB_CHUNK;

    char* w = (char*)d_ws;
    auto alloc = [&](size_t bytes) {
        char* p = w;
        w += (bytes + 255) & ~(size_t)255;
        return p;
    };
    int*    flag   = (int*)   alloc(4);
    int*    src32  = (int*)   alloc((size_t)E * 4);
    int*    dst32  = (int*)   alloc((size_t)E * 4);
    int*    counts = (int*)   alloc((size_t)NC * 4);
    int*    cbase  = (int*)   alloc((size_t)(NC + 1) * 4);
    int*    indeg  = (int*)   alloc((size_t)n * 4);
    float*  dinv   = (float*) alloc((size_t)n * 4);
    int*    ptr    = (int*)   alloc((size_t)(n + 1) * 4);
    int*    bsum   = (int*)   alloc(128 * 4);
    int*    boff   = (int*)   alloc(128 * 4);
    int*    cw     = (int*)   alloc((size_t)E * 4);
    int*    col    = (int*)   alloc((size_t)E * 4);
    __half* wfrag  = (__half*)alloc(16384 * 2);
    __half* wfrag2 = (__half*)alloc(8192 * 2);
    __half* H1     = (__half*)alloc((size_t)n * 64 * 2);
    __half* h1     = (__half*)alloc((size_t)n * 64 * 2);
    __half* A2     = (__half*)alloc((size_t)n * 64 * 2);

    int sbC = (NC + SCAN_ELEMS - 1) / SCAN_ELEMS;   // 98
    int sbN = (n  + SCAN_ELEMS - 1) / SCAN_ELEMS;   // 98

    detect_kernel<<<1, 128, 0, stream>>>(ei, flag);
    wfrag_kernel<<<64, 256, 0, stream>>>(W1, wfrag);
    wfrag2_kernel<<<32, 256, 0, stream>>>(W2, wfrag2);
    convert_count_kernel<<<NB_CHUNK, 256, 0, stream>>>(ei, src32, dst32, counts, E, CE, flag);
    scan_partial_kernel<<<sbC, 256, 0, stream>>>(counts, bsum, NC);
    scan_partials_kernel<<<1, 128, 0, stream>>>(bsum, boff, &cbase[NC], sbC);
    scan_write_kernel<<<sbC, 256, 0, stream>>>(counts, boff, cbase, NC);
    scatter_kernel<<<NB_CHUNK, 256, 0, stream>>>(src32, dst32, cbase, cw, E, CE);
    histdeg_kernel<<<NBUCK, 256, 0, stream>>>(cw, cbase, indeg, dinv, n);
    scan_partial_kernel<<<sbN, 256, 0, stream>>>(indeg, bsum, n);
    scan_partials_kernel<<<1, 128, 0, stream>>>(bsum, boff, &ptr[n], sbN);
    scan_write_kernel<<<sbN, 256, 0, stream>>>(indeg, boff, ptr, n);
    fillcol_kernel<<<NBUCK, 256, 0, stream>>>(cw, cbase, ptr, col, n);

    gemm1_kernel<<<(n + 63) / 64, 256, 0, stream>>>(x, wfrag, H1, n);
    aggregate_kernel<<<(n + 3) / 4, 256, 0, stream>>>(H1, ptr, col, dinv, b1, h1, n, 1, 1);
    aggregate_kernel<<<(n + 3) / 4, 256, 0, stream>>>(h1, ptr, col, dinv, nullptr, A2, n, 0, 1);
    gemm2_kernel<<<(n + 63) / 64, 256, 0, stream>>>(A2, wfrag2, b2, out, n);
}